// Round 2
// baseline (683.060 us; speedup 1.0000x reference)
//
#include <hip/hip_runtime.h>

// Problem constants
#define NN      81920
#define BB      4096
#define PP      20
#define DD      128
#define DOUTT   256
#define MAXDEGG 8

using bf16x8 = __attribute__((ext_vector_type(8))) short;
using f32x4  = __attribute__((ext_vector_type(4))) float;

static_assert(sizeof(bf16x8) == 16, "bf16x8 must be 16B");

__device__ __forceinline__ float b2f(ushort u) {
    union { unsigned u; float f; } v; v.u = ((unsigned)u) << 16; return v.f;
}
__device__ __forceinline__ ushort f2b(float f) {
    union { float f; unsigned u; } v; v.f = f;
    unsigned r = v.u + 0x7fffu + ((v.u >> 16) & 1u);
    return (ushort)(r >> 16);
}
__device__ __forceinline__ float sigm(float x) {
    return __fdividef(1.f, 1.f + __expf(-x));
}
__device__ __forceinline__ float tanh_fast(float x) {
    return 1.f - __fdividef(2.f, 1.f + __expf(2.f * x));
}
__device__ __forceinline__ f32x4 mfma16(bf16x8 a, bf16x8 b, f32x4 c) {
    return __builtin_amdgcn_mfma_f32_16x16x32_bf16(a, b, c, 0, 0, 0);
}
__device__ __forceinline__ bf16x8 ld8_bf(const ushort* p) {
    return *(const bf16x8*)p;
}
__device__ __forceinline__ bf16x8 ld8_f32(const float* p) {
    float4 a = *(const float4*)p;
    float4 b = *(const float4*)(p + 4);
    bf16x8 r;
    r[0] = (short)f2b(a.x); r[1] = (short)f2b(a.y);
    r[2] = (short)f2b(a.z); r[3] = (short)f2b(a.w);
    r[4] = (short)f2b(b.x); r[5] = (short)f2b(b.y);
    r[6] = (short)f2b(b.z); r[7] = (short)f2b(b.w);
    return r;
}

// ---------------- BatchNorm (batch stats over N rows, D=128 cols) ----------
// grid 640 blocks x 256 thr; each block covers 128 rows.
template <bool INF32>
__global__ __launch_bounds__(256) void bn_stats(const void* __restrict__ Xv,
                                                float* __restrict__ part) {
    const int tid  = threadIdx.x;
    const int col  = tid & 127;
    const int half = tid >> 7;
    const long base = (long)blockIdx.x * 128 + (long)half * 64;
    float s = 0.f, q = 0.f;
    for (int i = 0; i < 64; ++i) {
        float x;
        if (INF32) x = ((const float*)Xv)[(base + i) * 128 + col];
        else       x = b2f(((const ushort*)Xv)[(base + i) * 128 + col]);
        s += x; q += x * x;
    }
    __shared__ float red[2][2][128];
    red[0][half][col] = s;
    red[1][half][col] = q;
    __syncthreads();
    if (tid < 128) {
        part[blockIdx.x * 128 + tid]             = red[0][0][tid] + red[0][1][tid];
        part[640 * 128 + blockIdx.x * 128 + tid] = red[1][0][tid] + red[1][1][tid];
    }
}

// 1 block x 128 threads
__global__ void bn_final(const float* __restrict__ part,
                         const float* __restrict__ g, const float* __restrict__ b,
                         float2* __restrict__ ss) {
    const int c = threadIdx.x;
    float s = 0.f, q = 0.f;
    for (int i = 0; i < 640; ++i) {
        s += part[i * 128 + c];
        q += part[640 * 128 + i * 128 + c];
    }
    const float inv_n = 1.f / (float)NN;
    float mean = s * inv_n;
    float var  = q * inv_n - mean * mean;
    float rstd = rsqrtf(var + 1e-5f);
    float sc = g[c] * rstd;
    ss[c] = make_float2(sc, b[c] - mean * sc);
}

// grid 5120 x 256: each thread normalizes 8 contiguous elements -> bf16
template <bool INF32>
__global__ __launch_bounds__(256) void bn_apply(const void* __restrict__ Xv,
                                                const float2* __restrict__ ss,
                                                ushort* __restrict__ Y) {
    const long idx = (long)blockIdx.x * 256 + threadIdx.x;  // chunk of 8
    const int cg = (int)(idx & 15);
    float xv[8];
    if (INF32) {
        const float* X = (const float*)Xv;
        float4 a = *(const float4*)&X[idx * 8];
        float4 c = *(const float4*)&X[idx * 8 + 4];
        xv[0] = a.x; xv[1] = a.y; xv[2] = a.z; xv[3] = a.w;
        xv[4] = c.x; xv[5] = c.y; xv[6] = c.z; xv[7] = c.w;
    } else {
        bf16x8 x = *(const bf16x8*)&((const ushort*)Xv)[idx * 8];
#pragma unroll
        for (int j = 0; j < 8; ++j) xv[j] = b2f((ushort)x[j]);
    }
    bf16x8 y;
#pragma unroll
    for (int j = 0; j < 8; ++j) {
        float2 t = ss[cg * 8 + j];
        y[j] = (short)f2b(xv[j] * t.x + t.y);
    }
    *(bf16x8*)&Y[idx * 8] = y;
}

// ---------------- Generic GEMM: out[m,c] = sum_k A1[m,k]W1[c,k] (+A2W2) (+bias) (+out)
// A: [M,128] bf16 or f32 (optional row gather), W: [NCOL,128] f32 (cvt to bf16)
// block 256 (4 waves), BM=64, grid = M/64. Wave w owns cols [w*NCOL/4, ...).
template <int NCOL, int KPARTS, bool GATHER, bool ADDOUT, bool BIAS, bool AF32, bool OUTF32>
__global__ __launch_bounds__(256) void gemm_bt(const void* __restrict__ A1,
                                               const void* __restrict__ A2,
                                               const float* __restrict__ W1,
                                               const float* __restrict__ W2,
                                               const float* __restrict__ bias,
                                               const int* __restrict__ gidx,
                                               void* __restrict__ outv) {
    constexpr int JT = NCOL / 64;  // 16-col tiles per wave
    const int tid = threadIdx.x;
    const int w   = tid >> 6;
    const int l   = tid & 63;
    const int l15 = l & 15;
    const int l4  = l >> 4;
    const int colbase = w * (NCOL / 4);

    bf16x8 bfr[JT][KPARTS * 4];
#pragma unroll
    for (int jl = 0; jl < JT; ++jl) {
        const int wrow = colbase + jl * 16 + l15;
#pragma unroll
        for (int kp = 0; kp < KPARTS; ++kp) {
            const float* Wp = (kp == 0) ? W1 : W2;
#pragma unroll
            for (int kt = 0; kt < 4; ++kt)
                bfr[jl][kp * 4 + kt] = ld8_f32(&Wp[(long)wrow * 128 + kt * 32 + l4 * 8]);
        }
    }
    float bv[JT];
#pragma unroll
    for (int jl = 0; jl < JT; ++jl)
        bv[jl] = BIAS ? bias[colbase + jl * 16 + l15] : 0.f;

    const int rowblk = blockIdx.x * 64;
    const f32x4 fz = {0.f, 0.f, 0.f, 0.f};
#pragma unroll
    for (int it = 0; it < 4; ++it) {
        const int arow_l = rowblk + it * 16 + l15;
        const long arow = GATHER ? (long)gidx[arow_l] : (long)arow_l;
        bf16x8 afr[KPARTS * 4];
#pragma unroll
        for (int kp = 0; kp < KPARTS; ++kp) {
            const void* Ap = (kp == 0) ? A1 : A2;
#pragma unroll
            for (int kt = 0; kt < 4; ++kt) {
                if (AF32)
                    afr[kp * 4 + kt] = ld8_f32(&((const float*)Ap)[arow * 128 + kt * 32 + l4 * 8]);
                else
                    afr[kp * 4 + kt] = ld8_bf(&((const ushort*)Ap)[arow * 128 + kt * 32 + l4 * 8]);
            }
        }
        f32x4 acc[JT];
#pragma unroll
        for (int jl = 0; jl < JT; ++jl) {
            acc[jl] = fz;
#pragma unroll
            for (int kk = 0; kk < KPARTS * 4; ++kk)
                acc[jl] = mfma16(afr[kk], bfr[jl][kk], acc[jl]);
        }
#pragma unroll
        for (int jl = 0; jl < JT; ++jl) {
            const int col = colbase + jl * 16 + l15;
#pragma unroll
            for (int r = 0; r < 4; ++r) {
                const long orow = rowblk + it * 16 + l4 * 4 + r;
                float v = acc[jl][r];
                if (BIAS) v += bv[jl];
                if (OUTF32) {
                    float* op = (float*)outv + orow * NCOL + col;
                    if (ADDOUT) v += *op;
                    *op = v;
                } else {
                    ushort* op = (ushort*)outv + orow * NCOL + col;
                    if (ADDOUT) v += b2f(*op);
                    *op = f2b(v);
                }
            }
        }
    }
}

// ---------------- Fused ragged GRU over MAXDEG=8 neighbor steps ------------
// grid 1280 x 256 (4 waves), 64 nodes per block. h kept in LDS (double buf).
// Wave w owns cols [32w,32w+32); gate triple (c,c+128,c+256) is lane-local.
__global__ __launch_bounds__(256) void gru_kernel(const ushort* __restrict__ G,
                                                  const float* __restrict__ Whh,
                                                  const float* __restrict__ bhh,
                                                  const int* __restrict__ nbr_idx,
                                                  const int* __restrict__ deg,
                                                  ushort* __restrict__ neigh) {
    __shared__ alignas(16) ushort hbuf[2][64][136];  // +8 pad kills bank conflicts
    __shared__ alignas(16) int nbrs[64][8];
    __shared__ int degs[64];

    const int tid = threadIdx.x;
    const int w   = tid >> 6;
    const int l   = tid & 63;
    const int l15 = l & 15;
    const int l4  = l >> 4;
    const int blockRow = blockIdx.x * 64;
    const int colbase = w * 32;

    {   // zero both h buffers; stage nbr/deg
        bf16x8 z = {0, 0, 0, 0, 0, 0, 0, 0};
        bf16x8* p = (bf16x8*)&hbuf[0][0][0];
        for (int i = tid; i < 2 * 64 * 136 / 8; i += 256) p[i] = z;
        const int2* src = (const int2*)(nbr_idx + (long)blockRow * 8);
        ((int2*)&nbrs[0][0])[tid] = src[tid];
        if (tid < 64) degs[tid] = deg[blockRow + tid];
    }

    // W_hh fragments for this wave's 32 cols x 3 gates (stay in VGPRs)
    bf16x8 bfr[3][2][4];
#pragma unroll
    for (int g = 0; g < 3; ++g)
#pragma unroll
        for (int jp = 0; jp < 2; ++jp) {
            const int wrow = g * 128 + colbase + jp * 16 + l15;
#pragma unroll
            for (int kt = 0; kt < 4; ++kt)
                bfr[g][jp][kt] = ld8_f32(&Whh[(long)wrow * 128 + kt * 32 + l4 * 8]);
        }
    float bhv[2][3];
#pragma unroll
    for (int jp = 0; jp < 2; ++jp) {
        const int col = colbase + jp * 16 + l15;
        bhv[jp][0] = bhh[col];
        bhv[jp][1] = bhh[col + 128];
        bhv[jp][2] = bhh[col + 256];
    }
    __syncthreads();

    const f32x4 fz = {0.f, 0.f, 0.f, 0.f};
    for (int t = 0; t < 8; ++t) {
        const int cur = t & 1;
#pragma unroll
        for (int it = 0; it < 4; ++it) {
            bf16x8 af[4];
#pragma unroll
            for (int kt = 0; kt < 4; ++kt)
                af[kt] = *(const bf16x8*)&hbuf[cur][it * 16 + l15][kt * 32 + l4 * 8];
            f32x4 ar[2], az[2], an[2];
#pragma unroll
            for (int jp = 0; jp < 2; ++jp) {
                ar[jp] = fz; az[jp] = fz; an[jp] = fz;
#pragma unroll
                for (int kt = 0; kt < 4; ++kt) {
                    ar[jp] = mfma16(af[kt], bfr[0][jp][kt], ar[jp]);
                    az[jp] = mfma16(af[kt], bfr[1][jp][kt], az[jp]);
                    an[jp] = mfma16(af[kt], bfr[2][jp][kt], an[jp]);
                }
            }
#pragma unroll
            for (int r = 0; r < 4; ++r) {
                const int row = it * 16 + l4 * 4 + r;
                const int nbr = nbrs[row][t];
                const bool upd = (t < degs[row]);
                const ushort* Grow = G + (long)nbr * 384;
#pragma unroll
                for (int jp = 0; jp < 2; ++jp) {
                    const int col = colbase + jp * 16 + l15;
                    const float ir  = b2f(Grow[col]);
                    const float iz  = b2f(Grow[col + 128]);
                    const float in_ = b2f(Grow[col + 256]);
                    const float rr = sigm(ir + ar[jp][r] + bhv[jp][0]);
                    const float zz = sigm(iz + az[jp][r] + bhv[jp][1]);
                    const float nn = tanh_fast(in_ + rr * (an[jp][r] + bhv[jp][2]));
                    const ushort holdb = hbuf[cur][row][col];
                    const float hnew = (1.f - zz) * nn + zz * b2f(holdb);
                    hbuf[1 - cur][row][col] = upd ? f2b(hnew) : holdb;
                }
            }
        }
        __syncthreads();
    }
    // after t=7 (cur=1) the result is in hbuf[0]
    bf16x8* dst = (bf16x8*)(neigh + (long)blockRow * 128);
    for (int idx = tid; idx < 64 * 16; idx += 256) {
        const int row = idx >> 4, ch = idx & 15;
        dst[(long)row * 16 + ch] = *(const bf16x8*)&hbuf[0][row][ch * 8];
    }
}

// ---------------- e[node] = sum_c sigmoid(fu[node,c]+fvl[b,c]) * We[c] -----
// one wave per node row; grid 20480 x 256
__global__ __launch_bounds__(256) void e_kernel(const ushort* __restrict__ fu,
                                                const float* __restrict__ fvl,
                                                const float* __restrict__ We,
                                                float* __restrict__ e) {
    const int row = blockIdx.x * 4 + (threadIdx.x >> 6);
    const int l = threadIdx.x & 63;
    const int b = row / PP;
    float s = 0.f;
#pragma unroll
    for (int h = 0; h < 2; ++h) {
        const int c = l + 64 * h;
        const float x = b2f(fu[(long)row * 128 + c]) + fvl[(long)b * 128 + c];
        s += sigm(x) * We[c];
    }
#pragma unroll
    for (int off = 32; off > 0; off >>= 1) s += __shfl_xor(s, off, 64);
    if (l == 0) e[row] = s;
}

// ---------------- softmax over P=20 per graph; grid 16 x 256 ---------------
__global__ __launch_bounds__(256) void softmax_k(const float* __restrict__ e,
                                                 float* __restrict__ alpha) {
    const int b = blockIdx.x * 256 + threadIdx.x;
    float v[PP];
    float m = -1e30f;
#pragma unroll
    for (int p = 0; p < PP; ++p) { v[p] = e[b * PP + p]; m = fmaxf(m, v[p]); }
    float s = 0.f;
#pragma unroll
    for (int p = 0; p < PP; ++p) { v[p] = __expf(v[p] - m); s += v[p]; }
    const float inv = __fdividef(1.f, s);
#pragma unroll
    for (int p = 0; p < PP; ++p) alpha[b * PP + p] = v[p] * inv;
}

// ---------------- segment sums: s1 = sum_p alpha*h, s2 = sum_p pw*h --------
// 2 graphs per block (128 thr each); grid 2048 x 256
__global__ __launch_bounds__(256) void seg_k(const ushort* __restrict__ h,
                                             const float* __restrict__ alpha,
                                             const float* __restrict__ pw,
                                             ushort* __restrict__ s12) {
    const int g = blockIdx.x * 2 + (threadIdx.x >> 7);
    const int c = threadIdx.x & 127;
    float a1 = 0.f, a2 = 0.f;
#pragma unroll
    for (int p = 0; p < PP; ++p) {
        const int node = g * PP + p;
        const float hv = b2f(h[(long)node * 128 + c]);
        a1 += alpha[node] * hv;
        a2 += pw[node] * hv;
    }
    s12[(long)g * 128 + c]        = f2b(a1);
    s12[(long)(BB + g) * 128 + c] = f2b(a2);
}

// ---------------------------------------------------------------------------
extern "C" void kernel_launch(void* const* d_in, const int* in_sizes, int n_in,
                              void* d_out, int out_size, void* d_ws, size_t ws_size,
                              hipStream_t stream) {
    const float* feat    = (const float*)d_in[0];
    const float* intend  = (const float*)d_in[1];
    const float* pw      = (const float*)d_in[2];
    const int*   nbr_idx = (const int*)d_in[3];
    const int*   deg     = (const int*)d_in[4];
    const int*   last    = (const int*)d_in[5];
    const float* bn1_g   = (const float*)d_in[6];
    const float* bn1_b   = (const float*)d_in[7];
    const float* W_ih    = (const float*)d_in[8];
    const float* W_hh    = (const float*)d_in[9];
    const float* b_ih    = (const float*)d_in[10];
    const float* b_hh    = (const float*)d_in[11];
    const float* W_self  = (const float*)d_in[12];
    const float* W_neigh = (const float*)d_in[13];
    const float* bn2_g   = (const float*)d_in[14];
    const float* bn2_b   = (const float*)d_in[15];
    const float* Wu      = (const float*)d_in[16];
    const float* Wv      = (const float*)d_in[17];
    const float* bv      = (const float*)d_in[18];
    const float* Wi      = (const float*)d_in[19];
    const float* bi      = (const float*)d_in[20];
    const float* We      = (const float*)d_in[21];
    const float* Wout    = (const float*)d_in[22];
    float* out = (float*)d_out;
    char* ws = (char*)d_ws;

    // workspace layout (bytes); aliasing by liveness:
    //   h0 [N,128]b lives BN1->rst-gemm, then slot reused for hh
    //   G  [N,384]b lives Ggemm->gru;  rst (21MB) + fu (21MB) reuse G's slot
    ushort* h0    = (ushort*)(ws + 0L);              // 20,971,520
    ushort* hh    = h0;                              // reuse after rst gemm
    ushort* G     = (ushort*)(ws + 20971520L);       // 62,914,560
    ushort* rst   = G;                               // reuse (G dead after GRU)
    ushort* fu    = (ushort*)(ws + 41943040L);       // inside G slot, above rst
    ushort* neigh = (ushort*)(ws + 83886080L);       // 20,971,520
    float*  fvl   = (float*)(ws + 104857600L);       // 2,097,152
    float*  e     = (float*)(ws + 106954752L);       // 327,680
    float*  alpha = (float*)(ws + 107282432L);       // 327,680
    ushort* s12   = (ushort*)(ws + 107610112L);      // 2,097,152
    float*  part  = (float*)(ws + 109707264L);       // 655,360
    float2* ss1   = (float2*)(ws + 110362624L);      // 1,024
    float2* ss2   = (float2*)(ws + 110363648L);      // 1,024

    // ---- BN1 -> h0 (bf16) ----
    bn_stats<true><<<640, 256, 0, stream>>>(feat, part);
    bn_final<<<1, 128, 0, stream>>>(part, bn1_g, bn1_b, ss1);
    bn_apply<true><<<5120, 256, 0, stream>>>(feat, ss1, h0);

    // ---- G = h0 @ W_ih.T + b_ih ----
    gemm_bt<384, 1, false, false, true, false, false><<<1280, 256, 0, stream>>>(
        h0, nullptr, W_ih, nullptr, b_ih, nullptr, G);

    // ---- ragged GRU -> neigh ----
    gru_kernel<<<1280, 256, 0, stream>>>(G, W_hh, b_hh, nbr_idx, deg, neigh);

    // ---- rst = h0 @ W_self.T + neigh @ W_neigh.T ----
    gemm_bt<128, 2, false, false, false, false, false><<<1280, 256, 0, stream>>>(
        h0, neigh, W_self, W_neigh, nullptr, nullptr, rst);

    // ---- BN2 -> hh (bf16) ----
    bn_stats<false><<<640, 256, 0, stream>>>(rst, part);
    bn_final<<<1, 128, 0, stream>>>(part, bn2_g, bn2_b, ss2);
    bn_apply<false><<<5120, 256, 0, stream>>>(rst, ss2, hh);

    // ---- fvl = intend @ Wv.T + bv ; += hh[last] @ Wi.T + bi  (f32) ----
    gemm_bt<128, 1, false, false, true, true, true><<<64, 256, 0, stream>>>(
        intend, nullptr, Wv, nullptr, bv, nullptr, fvl);
    gemm_bt<128, 1, true, true, true, false, true><<<64, 256, 0, stream>>>(
        hh, nullptr, Wi, nullptr, bi, last, fvl);

    // ---- fu = hh @ Wu.T (bf16) ----
    gemm_bt<128, 1, false, false, false, false, false><<<1280, 256, 0, stream>>>(
        hh, nullptr, Wu, nullptr, nullptr, nullptr, fu);

    // ---- e, softmax, segment sums ----
    e_kernel<<<20480, 256, 0, stream>>>(fu, fvl, We, e);
    softmax_k<<<16, 256, 0, stream>>>(e, alpha);
    seg_k<<<2048, 256, 0, stream>>>(hh, alpha, pw, s12);

    // ---- [rst_g; pos] = s12 @ Wout.T -> d_out (f32) ----
    gemm_bt<256, 1, false, false, false, false, true><<<128, 256, 0, stream>>>(
        s12, nullptr, Wout, nullptr, nullptr, nullptr, out);

    (void)in_sizes; (void)n_in; (void)out_size; (void)ws_size;
}

// Round 3
// 427.582 us; speedup vs baseline: 1.5975x; 1.5975x over previous
//
#include <hip/hip_runtime.h>

// Problem constants
#define NN      81920
#define BB      4096
#define PP      20
#define DD      128
#define DOUTT   256
#define MAXDEGG 8

using bf16x8 = __attribute__((ext_vector_type(8))) short;
using f32x4  = __attribute__((ext_vector_type(4))) float;
using u16x4  = __attribute__((ext_vector_type(4))) ushort;

static_assert(sizeof(bf16x8) == 16, "bf16x8 must be 16B");
static_assert(sizeof(u16x4) == 8, "u16x4 must be 8B");

__device__ __forceinline__ float b2f(ushort u) {
    union { unsigned u; float f; } v; v.u = ((unsigned)u) << 16; return v.f;
}
__device__ __forceinline__ ushort f2b(float f) {
    union { float f; unsigned u; } v; v.f = f;
    unsigned r = v.u + 0x7fffu + ((v.u >> 16) & 1u);
    return (ushort)(r >> 16);
}
__device__ __forceinline__ float sigm(float x) {
    return __fdividef(1.f, 1.f + __expf(-x));
}
__device__ __forceinline__ float tanh_fast(float x) {
    return 1.f - __fdividef(2.f, 1.f + __expf(2.f * x));
}
__device__ __forceinline__ f32x4 mfma16(bf16x8 a, bf16x8 b, f32x4 c) {
    return __builtin_amdgcn_mfma_f32_16x16x32_bf16(a, b, c, 0, 0, 0);
}
__device__ __forceinline__ bf16x8 ld8_bf(const ushort* p) {
    return *(const bf16x8*)p;
}
__device__ __forceinline__ bf16x8 ld8_f32(const float* p) {
    float4 a = *(const float4*)p;
    float4 b = *(const float4*)(p + 4);
    bf16x8 r;
    r[0] = (short)f2b(a.x); r[1] = (short)f2b(a.y);
    r[2] = (short)f2b(a.z); r[3] = (short)f2b(a.w);
    r[4] = (short)f2b(b.x); r[5] = (short)f2b(b.y);
    r[6] = (short)f2b(b.z); r[7] = (short)f2b(b.w);
    return r;
}

// ---------------- BatchNorm (batch stats over N rows, D=128 cols) ----------
template <bool INF32>
__global__ __launch_bounds__(256) void bn_stats(const void* __restrict__ Xv,
                                                float* __restrict__ part) {
    const int tid  = threadIdx.x;
    const int col  = tid & 127;
    const int half = tid >> 7;
    const long base = (long)blockIdx.x * 128 + (long)half * 64;
    float s = 0.f, q = 0.f;
    for (int i = 0; i < 64; ++i) {
        float x;
        if (INF32) x = ((const float*)Xv)[(base + i) * 128 + col];
        else       x = b2f(((const ushort*)Xv)[(base + i) * 128 + col]);
        s += x; q += x * x;
    }
    __shared__ float red[2][2][128];
    red[0][half][col] = s;
    red[1][half][col] = q;
    __syncthreads();
    if (tid < 128) {
        part[blockIdx.x * 128 + tid]             = red[0][0][tid] + red[0][1][tid];
        part[640 * 128 + blockIdx.x * 128 + tid] = red[1][0][tid] + red[1][1][tid];
    }
}

// 1 block x 128 threads
__global__ void bn_final(const float* __restrict__ part,
                         const float* __restrict__ g, const float* __restrict__ b,
                         float2* __restrict__ ss) {
    const int c = threadIdx.x;
    float s = 0.f, q = 0.f;
    for (int i = 0; i < 640; ++i) {
        s += part[i * 128 + c];
        q += part[640 * 128 + i * 128 + c];
    }
    const float inv_n = 1.f / (float)NN;
    float mean = s * inv_n;
    float var  = q * inv_n - mean * mean;
    float rstd = rsqrtf(var + 1e-5f);
    float sc = g[c] * rstd;
    ss[c] = make_float2(sc, b[c] - mean * sc);
}

// grid 5120 x 256: each thread normalizes 8 contiguous elements -> bf16
template <bool INF32>
__global__ __launch_bounds__(256) void bn_apply(const void* __restrict__ Xv,
                                                const float2* __restrict__ ss,
                                                ushort* __restrict__ Y) {
    const long idx = (long)blockIdx.x * 256 + threadIdx.x;  // chunk of 8
    const int cg = (int)(idx & 15);
    float xv[8];
    if (INF32) {
        const float* X = (const float*)Xv;
        float4 a = *(const float4*)&X[idx * 8];
        float4 c = *(const float4*)&X[idx * 8 + 4];
        xv[0] = a.x; xv[1] = a.y; xv[2] = a.z; xv[3] = a.w;
        xv[4] = c.x; xv[5] = c.y; xv[6] = c.z; xv[7] = c.w;
    } else {
        bf16x8 x = *(const bf16x8*)&((const ushort*)Xv)[idx * 8];
#pragma unroll
        for (int j = 0; j < 8; ++j) xv[j] = b2f((ushort)x[j]);
    }
    bf16x8 y;
#pragma unroll
    for (int j = 0; j < 8; ++j) {
        float2 t = ss[cg * 8 + j];
        y[j] = (short)f2b(xv[j] * t.x + t.y);
    }
    *(bf16x8*)&Y[idx * 8] = y;
}

// ---------------- Generic GEMM: out[m,c] = sum_k A1[m,k]W1[c,k] (+A2W2) (+bias) (+out)
template <int NCOL, int KPARTS, bool GATHER, bool ADDOUT, bool BIAS, bool AF32, bool OUTF32>
__global__ __launch_bounds__(256) void gemm_bt(const void* __restrict__ A1,
                                               const void* __restrict__ A2,
                                               const float* __restrict__ W1,
                                               const float* __restrict__ W2,
                                               const float* __restrict__ bias,
                                               const int* __restrict__ gidx,
                                               void* __restrict__ outv) {
    constexpr int JT = NCOL / 64;  // 16-col tiles per wave
    const int tid = threadIdx.x;
    const int w   = tid >> 6;
    const int l   = tid & 63;
    const int l15 = l & 15;
    const int l4  = l >> 4;
    const int colbase = w * (NCOL / 4);

    bf16x8 bfr[JT][KPARTS * 4];
#pragma unroll
    for (int jl = 0; jl < JT; ++jl) {
        const int wrow = colbase + jl * 16 + l15;
#pragma unroll
        for (int kp = 0; kp < KPARTS; ++kp) {
            const float* Wp = (kp == 0) ? W1 : W2;
#pragma unroll
            for (int kt = 0; kt < 4; ++kt)
                bfr[jl][kp * 4 + kt] = ld8_f32(&Wp[(long)wrow * 128 + kt * 32 + l4 * 8]);
        }
    }
    float bv[JT];
#pragma unroll
    for (int jl = 0; jl < JT; ++jl)
        bv[jl] = BIAS ? bias[colbase + jl * 16 + l15] : 0.f;

    const int rowblk = blockIdx.x * 64;
    const f32x4 fz = {0.f, 0.f, 0.f, 0.f};
#pragma unroll
    for (int it = 0; it < 4; ++it) {
        const int arow_l = rowblk + it * 16 + l15;
        const long arow = GATHER ? (long)gidx[arow_l] : (long)arow_l;
        bf16x8 afr[KPARTS * 4];
#pragma unroll
        for (int kp = 0; kp < KPARTS; ++kp) {
            const void* Ap = (kp == 0) ? A1 : A2;
#pragma unroll
            for (int kt = 0; kt < 4; ++kt) {
                if (AF32)
                    afr[kp * 4 + kt] = ld8_f32(&((const float*)Ap)[arow * 128 + kt * 32 + l4 * 8]);
                else
                    afr[kp * 4 + kt] = ld8_bf(&((const ushort*)Ap)[arow * 128 + kt * 32 + l4 * 8]);
            }
        }
        f32x4 acc[JT];
#pragma unroll
        for (int jl = 0; jl < JT; ++jl) {
            acc[jl] = fz;
#pragma unroll
            for (int kk = 0; kk < KPARTS * 4; ++kk)
                acc[jl] = mfma16(afr[kk], bfr[jl][kk], acc[jl]);
        }
#pragma unroll
        for (int jl = 0; jl < JT; ++jl) {
            const int col = colbase + jl * 16 + l15;
#pragma unroll
            for (int r = 0; r < 4; ++r) {
                const long orow = rowblk + it * 16 + l4 * 4 + r;
                float v = acc[jl][r];
                if (BIAS) v += bv[jl];
                if (OUTF32) {
                    float* op = (float*)outv + orow * NCOL + col;
                    if (ADDOUT) v += *op;
                    *op = v;
                } else {
                    ushort* op = (ushort*)outv + orow * NCOL + col;
                    if (ADDOUT) v += b2f(*op);
                    *op = f2b(v);
                }
            }
        }
    }
}

// ---------------- Fused ragged GRU over MAXDEG=8 neighbor steps ------------
// 8 waves x 64 nodes per block; wave owns 16 cols. Swapped MFMA operands:
// output col(lane&15) = node row, rows(l4*4+r) = gate cols -> contiguous
// 4-col per-lane access for G gather / hbuf update (8B ops).
__global__ __launch_bounds__(512, 4) void gru_kernel(const ushort* __restrict__ G,
                                                     const float* __restrict__ Whh,
                                                     const float* __restrict__ bhh,
                                                     const int* __restrict__ nbr_idx,
                                                     const int* __restrict__ deg,
                                                     ushort* __restrict__ neigh) {
    __shared__ alignas(16) ushort hbuf[2][64][136];  // pad: 272B row stride
    __shared__ alignas(16) int nbrs[64][8];
    __shared__ int degs[64];

    const int tid = threadIdx.x;
    const int w   = tid >> 6;        // 0..7
    const int l   = tid & 63;
    const int l15 = l & 15;
    const int l4  = l >> 4;          // 0..3
    const int blockRow = blockIdx.x * 64;
    const int colbase = w * 16;
    const int c0 = colbase + l4 * 4; // lane's 4 contiguous cols

    {   // zero both h buffers; stage nbr/deg
        bf16x8 z = {0, 0, 0, 0, 0, 0, 0, 0};
        bf16x8* p = (bf16x8*)&hbuf[0][0][0];
        for (int i = tid; i < 2 * 64 * 136 / 8; i += 512) p[i] = z;
        ((int*)&nbrs[0][0])[tid] = nbr_idx[(long)blockRow * 8 + tid];
        if (tid < 64) degs[tid] = deg[blockRow + tid];
    }

    // W_hh fragments: 3 gates x 4 kt (48 VGPRs), wrow = gate*128 + colbase + l15
    bf16x8 bfr[3][4];
#pragma unroll
    for (int g = 0; g < 3; ++g)
#pragma unroll
        for (int kt = 0; kt < 4; ++kt)
            bfr[g][kt] = ld8_f32(&Whh[(long)(g * 128 + colbase + l15) * 128 + kt * 32 + l4 * 8]);
    // bias folded into accumulator init: acc[r] corresponds to col c0+r
    f32x4 binit[3];
#pragma unroll
    for (int g = 0; g < 3; ++g)
        binit[g] = *(const f32x4*)&bhh[g * 128 + c0];
    __syncthreads();

    int cur = 0;
    for (int t = 0; t < 8; ++t) {
#pragma unroll
        for (int it = 0; it < 4; ++it) {
            const int row = it * 16 + l15;
            const bool upd = (t < degs[row]);
            if (!__any(upd)) {  // whole 16-row group frozen: plain copy
                *(u16x4*)&hbuf[1 - cur][row][c0] = *(const u16x4*)&hbuf[cur][row][c0];
                continue;
            }
            // gather gi rows early (overlaps ds_reads + MFMAs below)
            u16x4 gi0 = {0, 0, 0, 0}, gi1 = {0, 0, 0, 0}, gi2 = {0, 0, 0, 0};
            if (upd) {
                const ushort* Grow = G + (long)nbrs[row][t] * 384;
                gi0 = *(const u16x4*)&Grow[c0];
                gi1 = *(const u16x4*)&Grow[c0 + 128];
                gi2 = *(const u16x4*)&Grow[c0 + 256];
            }
            bf16x8 af[4];
#pragma unroll
            for (int kt = 0; kt < 4; ++kt)
                af[kt] = *(const bf16x8*)&hbuf[cur][row][kt * 32 + l4 * 8];
            f32x4 ar = binit[0], az = binit[1], an = binit[2];
#pragma unroll
            for (int kt = 0; kt < 4; ++kt) {
                ar = mfma16(bfr[0][kt], af[kt], ar);
                az = mfma16(bfr[1][kt], af[kt], az);
                an = mfma16(bfr[2][kt], af[kt], an);
            }
            const u16x4 hold = *(const u16x4*)&hbuf[cur][row][c0];
            u16x4 hnew = hold;
            if (upd) {
#pragma unroll
                for (int r = 0; r < 4; ++r) {
                    const float rr = sigm(b2f(gi0[r]) + ar[r]);
                    const float zz = sigm(b2f(gi1[r]) + az[r]);
                    const float nn = tanh_fast(b2f(gi2[r]) + rr * an[r]);
                    hnew[r] = f2b((1.f - zz) * nn + zz * b2f(hold[r]));
                }
            }
            *(u16x4*)&hbuf[1 - cur][row][c0] = hnew;
        }
        __syncthreads();
        cur ^= 1;
    }
    // final state is in hbuf[0]
    bf16x8* dst = (bf16x8*)(neigh + (long)blockRow * 128);
    for (int idx = tid; idx < 64 * 16; idx += 512) {
        const int row = idx >> 4, ch = idx & 15;
        dst[(long)row * 16 + ch] = *(const bf16x8*)&hbuf[0][row][ch * 8];
    }
}

// ---------------- e[node] = sum_c sigmoid(fu[node,c]+fvl[b,c]) * We[c] -----
__global__ __launch_bounds__(256) void e_kernel(const ushort* __restrict__ fu,
                                                const float* __restrict__ fvl,
                                                const float* __restrict__ We,
                                                float* __restrict__ e) {
    const int row = blockIdx.x * 4 + (threadIdx.x >> 6);
    const int l = threadIdx.x & 63;
    const int b = row / PP;
    float s = 0.f;
#pragma unroll
    for (int h = 0; h < 2; ++h) {
        const int c = l + 64 * h;
        const float x = b2f(fu[(long)row * 128 + c]) + fvl[(long)b * 128 + c];
        s += sigm(x) * We[c];
    }
#pragma unroll
    for (int off = 32; off > 0; off >>= 1) s += __shfl_xor(s, off, 64);
    if (l == 0) e[row] = s;
}

// ---------------- softmax over P=20 per graph; grid 16 x 256 ---------------
__global__ __launch_bounds__(256) void softmax_k(const float* __restrict__ e,
                                                 float* __restrict__ alpha) {
    const int b = blockIdx.x * 256 + threadIdx.x;
    float v[PP];
    float m = -1e30f;
#pragma unroll
    for (int p = 0; p < PP; ++p) { v[p] = e[b * PP + p]; m = fmaxf(m, v[p]); }
    float s = 0.f;
#pragma unroll
    for (int p = 0; p < PP; ++p) { v[p] = __expf(v[p] - m); s += v[p]; }
    const float inv = __fdividef(1.f, s);
#pragma unroll
    for (int p = 0; p < PP; ++p) alpha[b * PP + p] = v[p] * inv;
}

// ---------------- segment sums: s1 = sum_p alpha*h, s2 = sum_p pw*h --------
__global__ __launch_bounds__(256) void seg_k(const ushort* __restrict__ h,
                                             const float* __restrict__ alpha,
                                             const float* __restrict__ pw,
                                             ushort* __restrict__ s12) {
    const int g = blockIdx.x * 2 + (threadIdx.x >> 7);
    const int c = threadIdx.x & 127;
    float a1 = 0.f, a2 = 0.f;
#pragma unroll
    for (int p = 0; p < PP; ++p) {
        const int node = g * PP + p;
        const float hv = b2f(h[(long)node * 128 + c]);
        a1 += alpha[node] * hv;
        a2 += pw[node] * hv;
    }
    s12[(long)g * 128 + c]        = f2b(a1);
    s12[(long)(BB + g) * 128 + c] = f2b(a2);
}

// ---------------------------------------------------------------------------
extern "C" void kernel_launch(void* const* d_in, const int* in_sizes, int n_in,
                              void* d_out, int out_size, void* d_ws, size_t ws_size,
                              hipStream_t stream) {
    const float* feat    = (const float*)d_in[0];
    const float* intend  = (const float*)d_in[1];
    const float* pw      = (const float*)d_in[2];
    const int*   nbr_idx = (const int*)d_in[3];
    const int*   deg     = (const int*)d_in[4];
    const int*   last    = (const int*)d_in[5];
    const float* bn1_g   = (const float*)d_in[6];
    const float* bn1_b   = (const float*)d_in[7];
    const float* W_ih    = (const float*)d_in[8];
    const float* W_hh    = (const float*)d_in[9];
    const float* b_ih    = (const float*)d_in[10];
    const float* b_hh    = (const float*)d_in[11];
    const float* W_self  = (const float*)d_in[12];
    const float* W_neigh = (const float*)d_in[13];
    const float* bn2_g   = (const float*)d_in[14];
    const float* bn2_b   = (const float*)d_in[15];
    const float* Wu      = (const float*)d_in[16];
    const float* Wv      = (const float*)d_in[17];
    const float* bv      = (const float*)d_in[18];
    const float* Wi      = (const float*)d_in[19];
    const float* bi      = (const float*)d_in[20];
    const float* We      = (const float*)d_in[21];
    const float* Wout    = (const float*)d_in[22];
    float* out = (float*)d_out;
    char* ws = (char*)d_ws;

    ushort* h0    = (ushort*)(ws + 0L);              // 20,971,520
    ushort* hh    = h0;                              // reuse after rst gemm
    ushort* G     = (ushort*)(ws + 20971520L);       // 62,914,560
    ushort* rst   = G;                               // reuse (G dead after GRU)
    ushort* fu    = (ushort*)(ws + 41943040L);       // inside G slot, above rst
    ushort* neigh = (ushort*)(ws + 83886080L);       // 20,971,520
    float*  fvl   = (float*)(ws + 104857600L);       // 2,097,152
    float*  e     = (float*)(ws + 106954752L);       // 327,680
    float*  alpha = (float*)(ws + 107282432L);       // 327,680
    ushort* s12   = (ushort*)(ws + 107610112L);      // 2,097,152
    float*  part  = (float*)(ws + 109707264L);       // 655,360
    float2* ss1   = (float2*)(ws + 110362624L);      // 1,024
    float2* ss2   = (float2*)(ws + 110363648L);      // 1,024

    // ---- BN1 -> h0 (bf16) ----
    bn_stats<true><<<640, 256, 0, stream>>>(feat, part);
    bn_final<<<1, 128, 0, stream>>>(part, bn1_g, bn1_b, ss1);
    bn_apply<true><<<5120, 256, 0, stream>>>(feat, ss1, h0);

    // ---- G = h0 @ W_ih.T + b_ih ----
    gemm_bt<384, 1, false, false, true, false, false><<<1280, 256, 0, stream>>>(
        h0, nullptr, W_ih, nullptr, b_ih, nullptr, G);

    // ---- ragged GRU -> neigh ----
    gru_kernel<<<1280, 512, 0, stream>>>(G, W_hh, b_hh, nbr_idx, deg, neigh);

    // ---- rst = h0 @ W_self.T + neigh @ W_neigh.T ----
    gemm_bt<128, 2, false, false, false, false, false><<<1280, 256, 0, stream>>>(
        h0, neigh, W_self, W_neigh, nullptr, nullptr, rst);

    // ---- BN2 -> hh (bf16) ----
    bn_stats<false><<<640, 256, 0, stream>>>(rst, part);
    bn_final<<<1, 128, 0, stream>>>(part, bn2_g, bn2_b, ss2);
    bn_apply<false><<<5120, 256, 0, stream>>>(rst, ss2, hh);

    // ---- fvl = intend @ Wv.T + bv ; += hh[last] @ Wi.T + bi  (f32) ----
    gemm_bt<128, 1, false, false, true, true, true><<<64, 256, 0, stream>>>(
        intend, nullptr, Wv, nullptr, bv, nullptr, fvl);
    gemm_bt<128, 1, true, true, true, false, true><<<64, 256, 0, stream>>>(
        hh, nullptr, Wi, nullptr, bi, last, fvl);

    // ---- fu = hh @ Wu.T (bf16) ----
    gemm_bt<128, 1, false, false, false, false, false><<<1280, 256, 0, stream>>>(
        hh, nullptr, Wu, nullptr, nullptr, nullptr, fu);

    // ---- e, softmax, segment sums ----
    e_kernel<<<20480, 256, 0, stream>>>(fu, fvl, We, e);
    softmax_k<<<16, 256, 0, stream>>>(e, alpha);
    seg_k<<<2048, 256, 0, stream>>>(hh, alpha, pw, s12);

    // ---- [rst_g; pos] = s12 @ Wout.T -> d_out (f32) ----
    gemm_bt<256, 1, false, false, false, false, true><<<128, 256, 0, stream>>>(
        s12, nullptr, Wout, nullptr, nullptr, nullptr, out);

    (void)in_sizes; (void)n_in; (void)out_size; (void)ws_size;
}